// Round 1
// baseline (2003.149 us; speedup 1.0000x reference)
//
#include <hip/hip_runtime.h>

#define HID 256
#define SB  16      // samples per block
#define TN  8       // columns per thread
#define TM  2       // samples per thread

typedef float v2f __attribute__((ext_vector_type(2)));
typedef float v4f __attribute__((ext_vector_type(4)));

__device__ __forceinline__ float fast_tanh(float x) {
    float ax = __builtin_fabsf(x);
    float e  = __expf(2.0f * ax);
    float t  = 1.0f - 2.0f * __builtin_amdgcn_rcpf(e + 1.0f);
    return __builtin_copysignf(t, x);
}

// LDS layout [n][s] with XOR swizzle on s to break write-side bank conflicts.
// Swizzle value is even (mask 14) so float2 (sample-pair) accesses stay aligned.
__device__ __forceinline__ int swz(int n, int s) {
    return n * SB + (s ^ ((n >> 2) & 14));
}

__device__ __forceinline__ v2f wave32_red(v2f v) {
#pragma unroll
    for (int m = 1; m <= 16; m <<= 1) {
        v.x += __shfl_xor(v.x, m, 64);
        v.y += __shfl_xor(v.y, m, 64);
    }
    return v;
}

__global__ void transpose256(const float* __restrict__ in, float* __restrict__ outT) {
    __shared__ float tile[32][33];
    const int tid = threadIdx.x;
    const int bx = blockIdx.x & 7;
    const int by = blockIdx.x >> 3;
    const int tx = tid & 31, ty = tid >> 5;
#pragma unroll
    for (int yy = ty; yy < 32; yy += 8)
        tile[yy][tx] = in[(by * 32 + yy) * HID + bx * 32 + tx];
    __syncthreads();
#pragma unroll
    for (int yy = ty; yy < 32; yy += 8)
        outT[(bx * 32 + yy) * HID + by * 32 + tx] = tile[tx][yy];
}

__launch_bounds__(256, 2)
__global__ void lnn_fused(
    const float* __restrict__ g_td, const float* __restrict__ g_sd,
    const float* __restrict__ g_th, const float* __restrict__ g_z,
    const float* __restrict__ g_s,  const float* __restrict__ g_sdd,
    const float* __restrict__ g_tau,
    const float* __restrict__ LW1, const float* __restrict__ Lb1,
    const float* __restrict__ LW2, const float* __restrict__ Lb2,
    const float* __restrict__ LW3,
    const float* __restrict__ BW1, const float* __restrict__ Bb1,
    const float* __restrict__ BW2, const float* __restrict__ Bb2,
    const float* __restrict__ W2T,
    float* __restrict__ out)
{
    __shared__ float ldsA [HID * SB];   // h1T, later dg2T (dir 2)
    __shared__ float ldsG [HID * SB];   // g2T
    __shared__ float ldsD0[HID * SB];   // dg2T dir 0
    __shared__ float ldsD1[HID * SB];   // dg2T dir 1
    __shared__ v4f   w1dir[HID];        // LW1 rows 0..2 (theta_dot)
    __shared__ v4f   w1th [HID];        // LW1 rows 6..8 (theta)
    __shared__ float xs[SB][16];        // [td3 sd3 th3 z1 s3 sdd3]
    __shared__ float red[SB][24];       // H9 C9 dL3 bout3

    const int tid = threadIdx.x;
    const int c   = tid & 31;
    const int r   = tid >> 5;
    const int k0  = c * TN;
    const int s0  = r * TM;
    const int sg0 = blockIdx.x * SB;

    // ---------------- stage inputs + LW1 rows ----------------
    if (tid < SB * 3) {
        int s = tid / 3, m = tid - s * 3;
        xs[s][m]      = g_td [(sg0 + s) * 3 + m];
        xs[s][3 + m]  = g_sd [(sg0 + s) * 3 + m];
        xs[s][6 + m]  = g_th [(sg0 + s) * 3 + m];
        xs[s][10 + m] = g_s  [(sg0 + s) * 3 + m];
        xs[s][13 + m] = g_sdd[(sg0 + s) * 3 + m];
    } else if (tid < SB * 3 + SB) {
        int s = tid - SB * 3;
        xs[s][9] = g_z[sg0 + s];
    }
    {
        int n = tid;  // 256 threads == HID
        w1dir[n] = (v4f){ LW1[0 * HID + n], LW1[1 * HID + n], LW1[2 * HID + n], 0.0f };
        w1th [n] = (v4f){ LW1[6 * HID + n], LW1[7 * HID + n], LW1[8 * HID + n], 0.0f };
    }
    __syncthreads();

    // ---------------- phase A: h1 = tanh(x @ LW1 + b1) ----------------
    float h1r[TM][TN];   // kept live through both passes (same tile mapping)
    {
        float a1v[TM][TN];
#pragma unroll
        for (int ss = 0; ss < TM; ++ss)
#pragma unroll
            for (int q = 0; q < TN; ++q) a1v[ss][q] = 0.0f;
#pragma unroll
        for (int m = 0; m < 10; ++m) {
            float w[TN];
            *(v4f*)(w)     = *(const v4f*)(LW1 + m * HID + k0);
            *(v4f*)(w + 4) = *(const v4f*)(LW1 + m * HID + k0 + 4);
#pragma unroll
            for (int ss = 0; ss < TM; ++ss) {
                float xm = xs[s0 + ss][m];
#pragma unroll
                for (int q = 0; q < TN; ++q)
                    a1v[ss][q] = __builtin_fmaf(xm, w[q], a1v[ss][q]);
            }
        }
        float bb[TN];
        *(v4f*)(bb)     = *(const v4f*)(Lb1 + k0);
        *(v4f*)(bb + 4) = *(const v4f*)(Lb1 + k0 + 4);
#pragma unroll
        for (int q = 0; q < TN; ++q) {
            h1r[0][q] = fast_tanh(a1v[0][q] + bb[q]);
            h1r[1][q] = fast_tanh(a1v[1][q] + bb[q]);
            v2f hw; hw.x = h1r[0][q]; hw.y = h1r[1][q];
            *(v2f*)&ldsA[swz(k0 + q, s0)] = hw;
        }
    }
    __syncthreads();

    // ---------------- pass 1: a2 + da2(dir 0..2), fused over n ----------------
    v2f acc[4][TN];
#pragma unroll
    for (int f = 0; f < 4; ++f)
#pragma unroll
        for (int q = 0; q < TN; ++q) acc[f][q] = (v2f){0.0f, 0.0f};

#pragma unroll 2
    for (int n = 0; n < HID; ++n) {
        v2f hv  = *(const v2f*)&ldsA[swz(n, s0)];
        v4f w1d = w1dir[n];
        float w[TN];
        *(v4f*)(w)     = *(const v4f*)(LW2 + n * HID + k0);
        *(v4f*)(w + 4) = *(const v4f*)(LW2 + n * HID + k0 + 4);
        v2f t1  = 1.0f - hv * hv;
        v2f in1 = t1 * w1d.x;
        v2f in2 = t1 * w1d.y;
        v2f in3 = t1 * w1d.z;
#pragma unroll
        for (int q = 0; q < TN; ++q) {
            acc[0][q] += hv  * w[q];
            acc[1][q] += in1 * w[q];
            acc[2][q] += in2 * w[q];
            acc[3][q] += in3 * w[q];
        }
    }
    __syncthreads();   // all h1T reads done; ldsA about to be overwritten

    // ---------------- pass 1 epilogue: h2, g2, dg2 -> LDS ----------------
    {
        float bb2[TN], w3v[TN];
        *(v4f*)(bb2)     = *(const v4f*)(Lb2 + k0);
        *(v4f*)(bb2 + 4) = *(const v4f*)(Lb2 + k0 + 4);
        *(v4f*)(w3v)     = *(const v4f*)(LW3 + k0);
        *(v4f*)(w3v + 4) = *(const v4f*)(LW3 + k0 + 4);
#pragma unroll
        for (int q = 0; q < TN; ++q) {
            int k = k0 + q;
            v2f a2 = acc[0][q] + bb2[q];
            v2f h2; h2.x = fast_tanh(a2.x); h2.y = fast_tanh(a2.y);
            v2f t2 = 1.0f - h2 * h2;
            v2f g2 = t2 * w3v[q];
            v2f m2 = -2.0f * h2 * g2;          // -2*h2*w3*t2
            *(v2f*)&ldsG [swz(k, s0)] = g2;
            *(v2f*)&ldsD0[swz(k, s0)] = m2 * acc[1][q];
            *(v2f*)&ldsD1[swz(k, s0)] = m2 * acc[2][q];
            *(v2f*)&ldsA [swz(k, s0)] = m2 * acc[3][q];
        }
    }
    __syncthreads();

    // ---------------- pass 2: u + du(dir 0..2) via W2T ----------------
#pragma unroll
    for (int f = 0; f < 4; ++f)
#pragma unroll
        for (int q = 0; q < TN; ++q) acc[f][q] = (v2f){0.0f, 0.0f};

#pragma unroll 2
    for (int k = 0; k < HID; ++k) {
        v2f g2v = *(const v2f*)&ldsG [swz(k, s0)];
        v2f d0v = *(const v2f*)&ldsD0[swz(k, s0)];
        v2f d1v = *(const v2f*)&ldsD1[swz(k, s0)];
        v2f d2v = *(const v2f*)&ldsA [swz(k, s0)];
        float w[TN];
        *(v4f*)(w)     = *(const v4f*)(W2T + k * HID + k0);
        *(v4f*)(w + 4) = *(const v4f*)(W2T + k * HID + k0 + 4);
#pragma unroll
        for (int q = 0; q < TN; ++q) {
            acc[0][q] += g2v * w[q];
            acc[1][q] += d0v * w[q];
            acc[2][q] += d1v * w[q];
            acc[3][q] += d2v * w[q];
        }
    }

    // ---------------- B_NN: Bout = tanh(xb@BW1+b)@BW2 ----------------
    v2f bp0 = (v2f){0.0f, 0.0f}, bp1 = (v2f){0.0f, 0.0f}, bp2 = (v2f){0.0f, 0.0f};
    {
        float abv[TM][TN];
#pragma unroll
        for (int ss = 0; ss < TM; ++ss)
#pragma unroll
            for (int q = 0; q < TN; ++q) abv[ss][q] = 0.0f;
#pragma unroll
        for (int m = 0; m < 9; ++m) {
            float w[TN];
            *(v4f*)(w)     = *(const v4f*)(BW1 + m * HID + k0);
            *(v4f*)(w + 4) = *(const v4f*)(BW1 + m * HID + k0 + 4);
            int xi = (m < 3) ? (6 + m) : (7 + m);   // th -> xs[6..8], s -> xs[10..12], sdd -> xs[13..15]
#pragma unroll
            for (int ss = 0; ss < TM; ++ss) {
                float xm = xs[s0 + ss][xi];
#pragma unroll
                for (int q = 0; q < TN; ++q)
                    abv[ss][q] = __builtin_fmaf(xm, w[q], abv[ss][q]);
            }
        }
        float bbv[TN];
        *(v4f*)(bbv)     = *(const v4f*)(Bb1 + k0);
        *(v4f*)(bbv + 4) = *(const v4f*)(Bb1 + k0 + 4);
#pragma unroll
        for (int q = 0; q < TN; ++q) {
            int k = k0 + q;
            v2f hb; hb.x = fast_tanh(abv[0][q] + bbv[q]); hb.y = fast_tanh(abv[1][q] + bbv[q]);
            bp0 += hb * BW2[k * 3 + 0];
            bp1 += hb * BW2[k * 3 + 1];
            bp2 += hb * BW2[k * 3 + 2];
        }
    }

    // ---------------- pass 2 epilogue: dg1, H/C/dL partials ----------------
    v2f Hp[3][3], Cp[3][3], dLp[3];
#pragma unroll
    for (int i = 0; i < 3; ++i) {
        dLp[i] = (v2f){0.0f, 0.0f};
#pragma unroll
        for (int j = 0; j < 3; ++j) { Hp[i][j] = (v2f){0.0f, 0.0f}; Cp[i][j] = (v2f){0.0f, 0.0f}; }
    }
#pragma unroll
    for (int q = 0; q < TN; ++q) {
        int n = k0 + q;
        v4f w1d = w1dir[n];
        v4f w1t = w1th[n];
        v2f h1; h1.x = h1r[0][q]; h1.y = h1r[1][q];
        v2f t1 = 1.0f - h1 * h1;
        v2f uu = acc[0][q];
        v2f g1 = uu * t1;
        dLp[0] += g1 * w1t.x; dLp[1] += g1 * w1t.y; dLp[2] += g1 * w1t.z;
        v2f um2h = -2.0f * uu * h1;
#pragma unroll
        for (int j = 0; j < 3; ++j) {
            float wj = (j == 0) ? w1d.x : (j == 1) ? w1d.y : w1d.z;
            v2f dh1 = t1 * wj;
            v2f dg1 = acc[1 + j][q] * t1 + um2h * dh1;
            Hp[0][j] += dg1 * w1d.x; Hp[1][j] += dg1 * w1d.y; Hp[2][j] += dg1 * w1d.z;
            Cp[0][j] += dg1 * w1t.x; Cp[1][j] += dg1 * w1t.y; Cp[2][j] += dg1 * w1t.z;
        }
    }

    // ---------------- reduce over 32 column-threads ----------------
#pragma unroll
    for (int i = 0; i < 3; ++i)
#pragma unroll
        for (int j = 0; j < 3; ++j) {
            v2f hv2 = wave32_red(Hp[i][j]);
            v2f cv2 = wave32_red(Cp[i][j]);
            if (c == 0) {
                red[s0][i * 3 + j]     = hv2.x; red[s0 + 1][i * 3 + j]     = hv2.y;
                red[s0][9 + i * 3 + j] = cv2.x; red[s0 + 1][9 + i * 3 + j] = cv2.y;
            }
        }
#pragma unroll
    for (int i = 0; i < 3; ++i) {
        v2f dv = wave32_red(dLp[i]);
        if (c == 0) { red[s0][18 + i] = dv.x; red[s0 + 1][18 + i] = dv.y; }
    }
    {
        v2f b0 = wave32_red(bp0), b1 = wave32_red(bp1), b2 = wave32_red(bp2);
        if (c == 0) {
            red[s0][21] = b0.x; red[s0 + 1][21] = b0.y;
            red[s0][22] = b1.x; red[s0 + 1][22] = b1.y;
            red[s0][23] = b2.x; red[s0 + 1][23] = b2.y;
        }
    }
    __syncthreads();

    // ---------------- per-sample 3x3 solve (fp64 Cramer) ----------------
    if (tid < SB) {
        int s = tid;
        int gs = sg0 + s;
        double H00 = red[s][0], H01 = red[s][1], H02 = red[s][2];
        double H10 = red[s][3], H11 = red[s][4], H12 = red[s][5];
        double H20 = red[s][6], H21 = red[s][7], H22 = red[s][8];
        double tdv0 = xs[s][0], tdv1 = xs[s][1], tdv2 = xs[s][2];
        double rhs[3];
#pragma unroll
        for (int i = 0; i < 3; ++i) {
            double Ci0 = red[s][9 + i * 3 + 0];
            double Ci1 = red[s][9 + i * 3 + 1];
            double Ci2 = red[s][9 + i * 3 + 2];
            rhs[i] = (double)g_tau[gs * 3 + i] + (double)red[s][21 + i] + (double)Bb2[i]
                   + (double)red[s][18 + i]
                   - (Ci0 * tdv0 + Ci1 * tdv1 + Ci2 * tdv2);
        }
        double c00 = H11 * H22 - H12 * H21;
        double c10 = H02 * H21 - H01 * H22;
        double c20 = H01 * H12 - H02 * H11;
        double c01 = H12 * H20 - H10 * H22;
        double c11 = H00 * H22 - H02 * H20;
        double c21 = H02 * H10 - H00 * H12;
        double c02 = H10 * H21 - H11 * H20;
        double c12 = H01 * H20 - H00 * H21;
        double c22 = H00 * H11 - H01 * H10;
        double det = H00 * c00 + H01 * c01 + H02 * c02;
        double inv = 1.0 / det;
        out[gs * 3 + 0] = (float)((c00 * rhs[0] + c10 * rhs[1] + c20 * rhs[2]) * inv);
        out[gs * 3 + 1] = (float)((c01 * rhs[0] + c11 * rhs[1] + c21 * rhs[2]) * inv);
        out[gs * 3 + 2] = (float)((c02 * rhs[0] + c12 * rhs[1] + c22 * rhs[2]) * inv);
    }
}

extern "C" void kernel_launch(void* const* d_in, const int* in_sizes, int n_in,
                              void* d_out, int out_size, void* d_ws, size_t ws_size,
                              hipStream_t stream) {
    const float* td  = (const float*)d_in[0];
    const float* sd  = (const float*)d_in[1];
    const float* th  = (const float*)d_in[2];
    const float* z   = (const float*)d_in[3];
    const float* s_  = (const float*)d_in[4];
    const float* sdd = (const float*)d_in[5];
    const float* tau = (const float*)d_in[6];
    const float* LW1 = (const float*)d_in[7];
    const float* Lb1 = (const float*)d_in[8];
    const float* LW2 = (const float*)d_in[9];
    const float* Lb2 = (const float*)d_in[10];
    const float* LW3 = (const float*)d_in[11];
    // d_in[12] = Lb3 (unused: constant bias does not affect any derivative)
    const float* BW1 = (const float*)d_in[13];
    const float* Bb1 = (const float*)d_in[14];
    const float* BW2 = (const float*)d_in[15];
    const float* Bb2 = (const float*)d_in[16];
    float* outp = (float*)d_out;
    float* W2T  = (float*)d_ws;   // 256*256*4 = 256 KB scratch

    transpose256<<<dim3(64), dim3(256), 0, stream>>>(LW2, W2T);

    const int Btot = in_sizes[0] / 3;
    const int nblk = Btot / SB;
    lnn_fused<<<dim3(nblk), dim3(256), 0, stream>>>(
        td, sd, th, z, s_, sdd, tau, LW1, Lb1, LW2, Lb2, LW3,
        BW1, Bb1, BW2, Bb2, W2T, outp);
}

// Round 2
// 1628.712 us; speedup vs baseline: 1.2299x; 1.2299x over previous
//
#include <hip/hip_runtime.h>

#define HID 256
#define SB  8       // samples per block
#define TN  4       // columns per thread (64 col-threads)
#define TM  2       // samples per thread (v2f packing)

typedef float v2f __attribute__((ext_vector_type(2)));
typedef float v4f __attribute__((ext_vector_type(4)));

__device__ __forceinline__ float fast_tanh(float x) {
    float ax = __builtin_fabsf(x);
    float e  = __expf(2.0f * ax);
    float t  = 1.0f - 2.0f * __builtin_amdgcn_rcpf(e + 1.0f);
    return __builtin_copysignf(t, x);
}

// ---- packed fp32 FMA/MUL with scalar broadcast from a register PAIR ----
// d = a * b.lo + c   (both halves use b's low float)
__device__ __forceinline__ v2f pk_fma_lo(v2f a, v2f b, v2f c) {
    asm("v_pk_fma_f32 %0, %1, %2, %0 op_sel_hi:[1,0,1]" : "+v"(c) : "v"(a), "v"(b));
    return c;
}
// d = a * b.hi + c
__device__ __forceinline__ v2f pk_fma_hi(v2f a, v2f b, v2f c) {
    asm("v_pk_fma_f32 %0, %1, %2, %0 op_sel:[0,1,0] op_sel_hi:[1,1,1]" : "+v"(c) : "v"(a), "v"(b));
    return c;
}
__device__ __forceinline__ v2f pk_mul_lo(v2f a, v2f b) {
    v2f d;
    asm("v_pk_mul_f32 %0, %1, %2 op_sel_hi:[1,0]" : "=v"(d) : "v"(a), "v"(b));
    return d;
}
__device__ __forceinline__ v2f pk_mul_hi(v2f a, v2f b) {
    v2f d;
    asm("v_pk_mul_f32 %0, %1, %2 op_sel:[0,1] op_sel_hi:[1,1]" : "=v"(d) : "v"(a), "v"(b));
    return d;
}

__device__ __forceinline__ v2f red64(v2f v) {
#pragma unroll
    for (int m = 1; m < 64; m <<= 1) {
        v.x += __shfl_xor(v.x, m, 64);
        v.y += __shfl_xor(v.y, m, 64);
    }
    return v;
}

__global__ void transpose256(const float* __restrict__ in, float* __restrict__ outT) {
    __shared__ float tile[32][33];
    const int tid = threadIdx.x;
    const int bx = blockIdx.x & 7;
    const int by = blockIdx.x >> 3;
    const int tx = tid & 31, ty = tid >> 5;
#pragma unroll
    for (int yy = ty; yy < 32; yy += 8)
        tile[yy][tx] = in[(by * 32 + yy) * HID + bx * 32 + tx];
    __syncthreads();
#pragma unroll
    for (int yy = ty; yy < 32; yy += 8)
        outT[(bx * 32 + yy) * HID + by * 32 + tx] = tile[tx][yy];
}

// update 4 column-accumulators of one family from weight pairs wlo/whi
#define ACC4(DST, SRC) \
    DST[0] = pk_fma_lo(SRC, wlo, DST[0]); \
    DST[1] = pk_fma_hi(SRC, wlo, DST[1]); \
    DST[2] = pk_fma_lo(SRC, whi, DST[2]); \
    DST[3] = pk_fma_hi(SRC, whi, DST[3]);

__launch_bounds__(256, 4)
__global__ void lnn_fused(
    const float* __restrict__ g_td, const float* __restrict__ g_sd,
    const float* __restrict__ g_th, const float* __restrict__ g_z,
    const float* __restrict__ g_s,  const float* __restrict__ g_sdd,
    const float* __restrict__ g_tau,
    const float* __restrict__ LW1, const float* __restrict__ Lb1,
    const float* __restrict__ LW2, const float* __restrict__ Lb2,
    const float* __restrict__ LW3,
    const float* __restrict__ BW1, const float* __restrict__ Bb1,
    const float* __restrict__ BW2, const float* __restrict__ Bb2,
    const float* __restrict__ W2T,
    float* __restrict__ out)
{
    // one packed LDS buffer, 32 floats per row n:
    //  pass1: row n holds [h1.x h1.y t1.x t1.y] per sample-pair (o = pr*4, XOR-swizzled)
    //  pass2: row k holds [g2.xy d0.xy | d1.xy d2.xy] per sample-pair (o = pr*8, swizzled)
    __shared__ __align__(16) float ldsP[HID * 32];
    __shared__ __align__(16) v4f   w1dir[HID];   // LW1 rows 0..2 (theta_dot dirs)
    __shared__ __align__(16) float xs2[16][SB];  // field-major inputs
    __shared__ __align__(16) float red[SB][21];  // H6 C9 dL3 B3

    const int tid = threadIdx.x;
    const int c   = tid & 63;          // column-thread 0..63
    const int r   = tid >> 6;          // sample-pair 0..3
    const int k0  = c * TN;
    const int s0  = r * TM;
    const int sg0 = blockIdx.x * SB;
    const int swm = (c & 7) << 2;      // this thread's row swizzle (rows k0..k0+3 share it)
    const int o1  = r * 4;             // pass1 slot
    const int o2  = r * 8;             // pass2 slot

    // ---------------- stage inputs + LW1 dir rows ----------------
    if (tid < SB * 3) {
        int s = tid / 3, m = tid - s * 3;
        xs2[m][s]      = g_td [(sg0 + s) * 3 + m];
        xs2[3 + m][s]  = g_sd [(sg0 + s) * 3 + m];
        xs2[6 + m][s]  = g_th [(sg0 + s) * 3 + m];
        xs2[10 + m][s] = g_s  [(sg0 + s) * 3 + m];
        xs2[13 + m][s] = g_sdd[(sg0 + s) * 3 + m];
    } else if (tid < SB * 3 + SB) {
        int s = tid - SB * 3;
        xs2[9][s] = g_z[sg0 + s];
    }
    {
        int n = tid;  // 256 threads == HID
        w1dir[n] = (v4f){ LW1[0 * HID + n], LW1[1 * HID + n], LW1[2 * HID + n], 0.0f };
    }
    __syncthreads();

    // ---------------- phase A: h1 = tanh(x @ LW1 + b1), stash {h1,t1} ----------------
    float h1r[TM][TN];
    {
        v2f a1[TN];
#pragma unroll
        for (int q = 0; q < TN; ++q) a1[q] = (v2f){0.0f, 0.0f};
#pragma unroll
        for (int m = 0; m < 10; ++m) {
            v4f w4 = *(const v4f*)(LW1 + m * HID + k0);
            v2f wlo = __builtin_shufflevector(w4, w4, 0, 1);
            v2f whi = __builtin_shufflevector(w4, w4, 2, 3);
            v2f xmv = *(const v2f*)&xs2[m][s0];
            ACC4(a1, xmv);
        }
        v4f bb = *(const v4f*)(Lb1 + k0);
#pragma unroll
        for (int q = 0; q < TN; ++q) {
            float hx = fast_tanh(a1[q].x + bb[q]);
            float hy = fast_tanh(a1[q].y + bb[q]);
            h1r[0][q] = hx; h1r[1][q] = hy;
            v4f pk = (v4f){ hx, hy, 1.0f - hx * hx, 1.0f - hy * hy };
            *(v4f*)&ldsP[(k0 + q) * 32 + (o1 ^ swm)] = pk;
        }
    }

    // ---------------- B_NN early (keeps regs off the hot loops) ----------------
    {
        v2f ab[TN];
#pragma unroll
        for (int q = 0; q < TN; ++q) ab[q] = (v2f){0.0f, 0.0f};
#pragma unroll
        for (int m = 0; m < 9; ++m) {
            v4f w4 = *(const v4f*)(BW1 + m * HID + k0);
            v2f wlo = __builtin_shufflevector(w4, w4, 0, 1);
            v2f whi = __builtin_shufflevector(w4, w4, 2, 3);
            int xi = (m < 3) ? (6 + m) : (7 + m);
            v2f xmv = *(const v2f*)&xs2[xi][s0];
            ACC4(ab, xmv);
        }
        v4f bbv = *(const v4f*)(Bb1 + k0);
        v2f bp0 = (v2f){0,0}, bp1 = (v2f){0,0}, bp2 = (v2f){0,0};
#pragma unroll
        for (int q = 0; q < TN; ++q) {
            int k = k0 + q;
            v2f hb; hb.x = fast_tanh(ab[q].x + bbv[q]); hb.y = fast_tanh(ab[q].y + bbv[q]);
            bp0 += hb * BW2[k * 3 + 0];
            bp1 += hb * BW2[k * 3 + 1];
            bp2 += hb * BW2[k * 3 + 2];
        }
        bp0 = red64(bp0); bp1 = red64(bp1); bp2 = red64(bp2);
        if (c == 0) {
            red[s0][18] = bp0.x; red[s0 + 1][18] = bp0.y;
            red[s0][19] = bp1.x; red[s0 + 1][19] = bp1.y;
            red[s0][20] = bp2.x; red[s0 + 1][20] = bp2.y;
        }
    }
    __syncthreads();

    // ---------------- pass 1: a2 + da2(dir0..2) ----------------
    v2f acc[4][TN];
#pragma unroll
    for (int f = 0; f < 4; ++f)
#pragma unroll
        for (int q = 0; q < TN; ++q) acc[f][q] = (v2f){0.0f, 0.0f};

    for (int n0 = 0; n0 < HID; n0 += 4) {
        int sw = ((n0 >> 2) & 7) << 2;
        const float* prow = &ldsP[n0 * 32 + (o1 ^ sw)];
        const float* wrow = LW2 + n0 * HID + k0;
#pragma unroll
        for (int j = 0; j < 4; ++j) {
            v4f ht = *(const v4f*)(prow + j * 32);      // [h1x h1y t1x t1y]
            v4f wd = w1dir[n0 + j];
            v4f w4 = *(const v4f*)(wrow + j * HID);
            v2f wlo = __builtin_shufflevector(w4, w4, 0, 1);
            v2f whi = __builtin_shufflevector(w4, w4, 2, 3);
            v2f hv = __builtin_shufflevector(ht, ht, 0, 1);
            v2f t1 = __builtin_shufflevector(ht, ht, 2, 3);
            v2f wdlo = __builtin_shufflevector(wd, wd, 0, 1);
            v2f wdhi = __builtin_shufflevector(wd, wd, 2, 3);
            v2f in1 = pk_mul_lo(t1, wdlo);
            v2f in2 = pk_mul_hi(t1, wdlo);
            v2f in3 = pk_mul_lo(t1, wdhi);
            ACC4(acc[0], hv);
            ACC4(acc[1], in1);
            ACC4(acc[2], in2);
            ACC4(acc[3], in3);
        }
    }
    __syncthreads();   // everyone done reading {h1,t1} rows

    // ---------------- pass-1 epilogue: pack {g2,d0,d1,d2} ----------------
    {
        v4f b2v = *(const v4f*)(Lb2 + k0);
        v4f w3v = *(const v4f*)(LW3 + k0);
#pragma unroll
        for (int q = 0; q < TN; ++q) {
            v2f a2 = acc[0][q] + b2v[q];
            v2f h2; h2.x = fast_tanh(a2.x); h2.y = fast_tanh(a2.y);
            v2f t2 = 1.0f - h2 * h2;
            v2f g2 = t2 * w3v[q];
            v2f m2 = -2.0f * h2 * g2;
            v2f d0 = m2 * acc[1][q];
            v2f d1 = m2 * acc[2][q];
            v2f d2 = m2 * acc[3][q];
            int rb = (k0 + q) * 32;
            int b1 = o2 ^ swm;
            *(v4f*)&ldsP[rb + b1]       = (v4f){ g2.x, g2.y, d0.x, d0.y };
            *(v4f*)&ldsP[rb + (b1 ^ 4)] = (v4f){ d1.x, d1.y, d2.x, d2.y };
        }
    }
    __syncthreads();

    // ---------------- pass 2: u + du(dir0..2) via W2T ----------------
#pragma unroll
    for (int f = 0; f < 4; ++f)
#pragma unroll
        for (int q = 0; q < TN; ++q) acc[f][q] = (v2f){0.0f, 0.0f};

    for (int n0 = 0; n0 < HID; n0 += 4) {
        int sw = ((n0 >> 2) & 7) << 2;
        int b1 = o2 ^ sw;
        const float* prow = &ldsP[n0 * 32];
        const float* wrow = W2T + n0 * HID + k0;
#pragma unroll
        for (int j = 0; j < 4; ++j) {
            v4f pA = *(const v4f*)(prow + j * 32 + b1);        // [g2x g2y d0x d0y]
            v4f pB = *(const v4f*)(prow + j * 32 + (b1 ^ 4));  // [d1x d1y d2x d2y]
            v4f w4 = *(const v4f*)(wrow + j * HID);
            v2f wlo = __builtin_shufflevector(w4, w4, 0, 1);
            v2f whi = __builtin_shufflevector(w4, w4, 2, 3);
            v2f g2v = __builtin_shufflevector(pA, pA, 0, 1);
            v2f d0v = __builtin_shufflevector(pA, pA, 2, 3);
            v2f d1v = __builtin_shufflevector(pB, pB, 0, 1);
            v2f d2v = __builtin_shufflevector(pB, pB, 2, 3);
            ACC4(acc[0], g2v);
            ACC4(acc[1], d0v);
            ACC4(acc[2], d1v);
            ACC4(acc[3], d2v);
        }
    }

    // ---------------- epilogue: dg1 -> H(sym6)/C/dL partials ----------------
    v2f Hp[6], Cp[3][3], dLp[3];
#pragma unroll
    for (int i = 0; i < 6; ++i) Hp[i] = (v2f){0.0f, 0.0f};
#pragma unroll
    for (int i = 0; i < 3; ++i) {
        dLp[i] = (v2f){0.0f, 0.0f};
#pragma unroll
        for (int j = 0; j < 3; ++j) Cp[i][j] = (v2f){0.0f, 0.0f};
    }
    {
        v4f wd0 = *(const v4f*)(LW1 + 0 * HID + k0);
        v4f wd1 = *(const v4f*)(LW1 + 1 * HID + k0);
        v4f wd2 = *(const v4f*)(LW1 + 2 * HID + k0);
        v4f wt0 = *(const v4f*)(LW1 + 6 * HID + k0);
        v4f wt1 = *(const v4f*)(LW1 + 7 * HID + k0);
        v4f wt2 = *(const v4f*)(LW1 + 8 * HID + k0);
#pragma unroll
        for (int q = 0; q < TN; ++q) {
            v2f h1; h1.x = h1r[0][q]; h1.y = h1r[1][q];
            v2f t1 = 1.0f - h1 * h1;
            v2f uu = acc[0][q];
            v2f g1 = uu * t1;
            float wdq[3] = { wd0[q], wd1[q], wd2[q] };
            float wtq[3] = { wt0[q], wt1[q], wt2[q] };
            dLp[0] += g1 * wtq[0]; dLp[1] += g1 * wtq[1]; dLp[2] += g1 * wtq[2];
            v2f um2h = -2.0f * uu * h1;
            v2f dg1[3];
#pragma unroll
            for (int j = 0; j < 3; ++j) {
                v2f dh1 = t1 * wdq[j];
                dg1[j] = acc[1 + j][q] * t1 + um2h * dh1;
#pragma unroll
                for (int i = 0; i < 3; ++i)
                    Cp[i][j] += dg1[j] * wtq[i];
            }
            // symmetric H: (0,0) (0,1) (1,1) (0,2) (1,2) (2,2)
            Hp[0] += dg1[0] * wdq[0];
            Hp[1] += dg1[1] * wdq[0];
            Hp[2] += dg1[1] * wdq[1];
            Hp[3] += dg1[2] * wdq[0];
            Hp[4] += dg1[2] * wdq[1];
            Hp[5] += dg1[2] * wdq[2];
        }
    }

    // ---------------- reduce over 64 column-threads ----------------
#pragma unroll
    for (int i = 0; i < 6; ++i) {
        v2f v = red64(Hp[i]);
        if (c == 0) { red[s0][i] = v.x; red[s0 + 1][i] = v.y; }
    }
#pragma unroll
    for (int i = 0; i < 3; ++i)
#pragma unroll
        for (int j = 0; j < 3; ++j) {
            v2f v = red64(Cp[i][j]);
            if (c == 0) { red[s0][6 + i * 3 + j] = v.x; red[s0 + 1][6 + i * 3 + j] = v.y; }
        }
#pragma unroll
    for (int i = 0; i < 3; ++i) {
        v2f v = red64(dLp[i]);
        if (c == 0) { red[s0][15 + i] = v.x; red[s0 + 1][15 + i] = v.y; }
    }
    __syncthreads();

    // ---------------- per-sample 3x3 symmetric solve (fp64) ----------------
    if (tid < SB) {
        int s = tid;
        int gs = sg0 + s;
        double Ha = red[s][0], Hb = red[s][1], Hd = red[s][2];
        double Hc = red[s][3], He = red[s][4], Hf = red[s][5];
        double td0 = xs2[0][s], td1 = xs2[1][s], td2 = xs2[2][s];
        double rhs[3];
#pragma unroll
        for (int i = 0; i < 3; ++i) {
            double Ci0 = red[s][6 + i * 3 + 0];
            double Ci1 = red[s][6 + i * 3 + 1];
            double Ci2 = red[s][6 + i * 3 + 2];
            rhs[i] = (double)g_tau[gs * 3 + i] + (double)red[s][18 + i] + (double)Bb2[i]
                   + (double)red[s][15 + i]
                   - (Ci0 * td0 + Ci1 * td1 + Ci2 * td2);
        }
        double I00 = Hd * Hf - He * He;
        double I01 = Hc * He - Hb * Hf;
        double I02 = Hb * He - Hc * Hd;
        double I11 = Ha * Hf - Hc * Hc;
        double I12 = Hb * Hc - Ha * He;
        double I22 = Ha * Hd - Hb * Hb;
        double det = Ha * I00 + Hb * I01 + Hc * I02;
        double inv = 1.0 / det;
        out[gs * 3 + 0] = (float)((I00 * rhs[0] + I01 * rhs[1] + I02 * rhs[2]) * inv);
        out[gs * 3 + 1] = (float)((I01 * rhs[0] + I11 * rhs[1] + I12 * rhs[2]) * inv);
        out[gs * 3 + 2] = (float)((I02 * rhs[0] + I12 * rhs[1] + I22 * rhs[2]) * inv);
    }
}

extern "C" void kernel_launch(void* const* d_in, const int* in_sizes, int n_in,
                              void* d_out, int out_size, void* d_ws, size_t ws_size,
                              hipStream_t stream) {
    const float* td  = (const float*)d_in[0];
    const float* sd  = (const float*)d_in[1];
    const float* th  = (const float*)d_in[2];
    const float* z   = (const float*)d_in[3];
    const float* s_  = (const float*)d_in[4];
    const float* sdd = (const float*)d_in[5];
    const float* tau = (const float*)d_in[6];
    const float* LW1 = (const float*)d_in[7];
    const float* Lb1 = (const float*)d_in[8];
    const float* LW2 = (const float*)d_in[9];
    const float* Lb2 = (const float*)d_in[10];
    const float* LW3 = (const float*)d_in[11];
    // d_in[12] = Lb3 (unused: constant bias does not affect any derivative)
    const float* BW1 = (const float*)d_in[13];
    const float* Bb1 = (const float*)d_in[14];
    const float* BW2 = (const float*)d_in[15];
    const float* Bb2 = (const float*)d_in[16];
    float* outp = (float*)d_out;
    float* W2T  = (float*)d_ws;   // 256*256*4 = 256 KB scratch

    transpose256<<<dim3(64), dim3(256), 0, stream>>>(LW2, W2T);

    const int Btot = in_sizes[0] / 3;
    const int nblk = Btot / SB;
    lnn_fused<<<dim3(nblk), dim3(256), 0, stream>>>(
        td, sd, th, z, s_, sdd, tau, LW1, Lb1, LW2, Lb2, LW3,
        BW1, Bb1, BW2, Bb2, W2T, outp);
}

// Round 3
// 1281.750 us; speedup vs baseline: 1.5628x; 1.2707x over previous
//
#include <hip/hip_runtime.h>

#define HID 256
#define SB  8       // samples per block
#define TN  4       // columns per thread (64 col-threads)
#define TM  2       // samples per thread (v2f packing)

typedef float v2f __attribute__((ext_vector_type(2)));
typedef float v4f __attribute__((ext_vector_type(4)));

__device__ __forceinline__ float fast_tanh(float x) {
    float ax = __builtin_fabsf(x);
    float e  = __expf(2.0f * ax);
    float t  = 1.0f - 2.0f * __builtin_amdgcn_rcpf(e + 1.0f);
    return __builtin_copysignf(t, x);
}

// ---- packed fp32 FMA with scalar broadcast from a register PAIR ----
// c += a * b.lo (both halves of a scaled by b's low float)
__device__ __forceinline__ v2f pk_fma_lo(v2f a, v2f b, v2f c) {
    asm("v_pk_fma_f32 %0, %1, %2, %0 op_sel_hi:[1,0,1]" : "+v"(c) : "v"(a), "v"(b));
    return c;
}
// c += a * b.hi
__device__ __forceinline__ v2f pk_fma_hi(v2f a, v2f b, v2f c) {
    asm("v_pk_fma_f32 %0, %1, %2, %0 op_sel:[0,1,0] op_sel_hi:[1,1,1]" : "+v"(c) : "v"(a), "v"(b));
    return c;
}

__device__ __forceinline__ v2f red64(v2f v) {
#pragma unroll
    for (int m = 1; m < 64; m <<= 1) {
        v.x += __shfl_xor(v.x, m, 64);
        v.y += __shfl_xor(v.y, m, 64);
    }
    return v;
}

__global__ void transpose256(const float* __restrict__ in, float* __restrict__ outT) {
    __shared__ float tile[32][33];
    const int tid = threadIdx.x;
    const int bx = blockIdx.x & 7;
    const int by = blockIdx.x >> 3;
    const int tx = tid & 31, ty = tid >> 5;
#pragma unroll
    for (int yy = ty; yy < 32; yy += 8)
        tile[yy][tx] = in[(by * 32 + yy) * HID + bx * 32 + tx];
    __syncthreads();
#pragma unroll
    for (int yy = ty; yy < 32; yy += 8)
        outT[(bx * 32 + yy) * HID + by * 32 + tx] = tile[tx][yy];
}

// update 4 column-accumulators of one family from weight pairs wlo/whi
#define ACC4(DST, SRC) \
    DST[0] = pk_fma_lo(SRC, wlo, DST[0]); \
    DST[1] = pk_fma_hi(SRC, wlo, DST[1]); \
    DST[2] = pk_fma_lo(SRC, whi, DST[2]); \
    DST[3] = pk_fma_hi(SRC, whi, DST[3]);

__launch_bounds__(256, 4)
__global__ void lnn_fused(
    const float* __restrict__ g_td, const float* __restrict__ g_sd,
    const float* __restrict__ g_th, const float* __restrict__ g_z,
    const float* __restrict__ g_s,  const float* __restrict__ g_sdd,
    const float* __restrict__ g_tau,
    const float* __restrict__ LW1, const float* __restrict__ Lb1,
    const float* __restrict__ LW2, const float* __restrict__ Lb2,
    const float* __restrict__ LW3,
    const float* __restrict__ BW1, const float* __restrict__ Bb1,
    const float* __restrict__ BW2, const float* __restrict__ Bb2,
    const float* __restrict__ W2T,
    float* __restrict__ out)
{
    // packed LDS, 32 floats per row n:
    //  pass1: row n, pair r at slot (r*8)^swz: [h1x h1y p0x p0y | p1x p1y p2x p2y]
    //         where pj = t1 * W1d_j  (pre-scaled forward tangents)
    //  pass2: row k, pair r at slot (r*4)^swz: [g2x g2y pdx pdy]
    //         where pd = m2 * (P @ theta_dot)
    __shared__ __align__(16) float ldsP[HID * 32];
    __shared__ __align__(16) float xs2[16][SB];  // field-major inputs
    __shared__ __align__(16) float red[SB][16];  // H6 dL3 Ct3 B3

    const int tid = threadIdx.x;
    const int c   = tid & 63;          // column-thread 0..63
    const int r   = tid >> 6;          // sample-pair 0..3
    const int k0  = c * TN;
    const int s0  = r * TM;
    const int sg0 = blockIdx.x * SB;
    const int o1  = r * 8;             // pass1 slot
    const int o2  = r * 4;             // pass2 slot
    const int sw1 = (c & 3) << 3;      // row-group swizzle for this thread's rows
    const int sw2 = (c & 3) << 2;

    // ---------------- stage inputs ----------------
    if (tid < SB * 3) {
        int s = tid / 3, m = tid - s * 3;
        xs2[m][s]      = g_td [(sg0 + s) * 3 + m];
        xs2[3 + m][s]  = g_sd [(sg0 + s) * 3 + m];
        xs2[6 + m][s]  = g_th [(sg0 + s) * 3 + m];
        xs2[10 + m][s] = g_s  [(sg0 + s) * 3 + m];
        xs2[13 + m][s] = g_sdd[(sg0 + s) * 3 + m];
    } else if (tid < SB * 3 + SB) {
        int s = tid - SB * 3;
        xs2[9][s] = g_z[sg0 + s];
    }
    __syncthreads();

    // ---------------- phase A: h1 = tanh(x @ LW1 + b1), stash {h1, t1*w1d_j} ----------------
    float h1r[TM][TN];
    {
        v2f a1[TN];
#pragma unroll
        for (int q = 0; q < TN; ++q) a1[q] = (v2f){0.0f, 0.0f};
#pragma unroll
        for (int m = 0; m < 10; ++m) {
            v4f w4 = *(const v4f*)(LW1 + m * HID + k0);
            v2f wlo = __builtin_shufflevector(w4, w4, 0, 1);
            v2f whi = __builtin_shufflevector(w4, w4, 2, 3);
            v2f xmv = *(const v2f*)&xs2[m][s0];
            ACC4(a1, xmv);
        }
        v4f bb  = *(const v4f*)(Lb1 + k0);
        v4f wd0 = *(const v4f*)(LW1 + 0 * HID + k0);
        v4f wd1 = *(const v4f*)(LW1 + 1 * HID + k0);
        v4f wd2 = *(const v4f*)(LW1 + 2 * HID + k0);
#pragma unroll
        for (int q = 0; q < TN; ++q) {
            float hx = fast_tanh(a1[q].x + bb[q]);
            float hy = fast_tanh(a1[q].y + bb[q]);
            h1r[0][q] = hx; h1r[1][q] = hy;
            float tx = 1.0f - hx * hx, ty = 1.0f - hy * hy;
            int rb = (k0 + q) * 32 + (o1 ^ sw1);
            *(v4f*)&ldsP[rb]     = (v4f){ hx, hy, tx * wd0[q], ty * wd0[q] };
            *(v4f*)&ldsP[rb + 4] = (v4f){ tx * wd1[q], ty * wd1[q], tx * wd2[q], ty * wd2[q] };
        }
    }

    // ---------------- B_NN early ----------------
    {
        v2f ab[TN];
#pragma unroll
        for (int q = 0; q < TN; ++q) ab[q] = (v2f){0.0f, 0.0f};
#pragma unroll
        for (int m = 0; m < 9; ++m) {
            v4f w4 = *(const v4f*)(BW1 + m * HID + k0);
            v2f wlo = __builtin_shufflevector(w4, w4, 0, 1);
            v2f whi = __builtin_shufflevector(w4, w4, 2, 3);
            int xi = (m < 3) ? (6 + m) : (7 + m);
            v2f xmv = *(const v2f*)&xs2[xi][s0];
            ACC4(ab, xmv);
        }
        v4f bbv = *(const v4f*)(Bb1 + k0);
        v2f bp0 = (v2f){0,0}, bp1 = (v2f){0,0}, bp2 = (v2f){0,0};
#pragma unroll
        for (int q = 0; q < TN; ++q) {
            int k = k0 + q;
            v2f hb; hb.x = fast_tanh(ab[q].x + bbv[q]); hb.y = fast_tanh(ab[q].y + bbv[q]);
            bp0 += hb * BW2[k * 3 + 0];
            bp1 += hb * BW2[k * 3 + 1];
            bp2 += hb * BW2[k * 3 + 2];
        }
        bp0 = red64(bp0); bp1 = red64(bp1); bp2 = red64(bp2);
        if (c == 0) {
            red[s0][12] = bp0.x; red[s0 + 1][12] = bp0.y;
            red[s0][13] = bp1.x; red[s0 + 1][13] = bp1.y;
            red[s0][14] = bp2.x; red[s0 + 1][14] = bp2.y;
        }
    }
    __syncthreads();

    // ---------------- pass 1: a2 + P_j = W2^T(t1*w1d_j), j=0..2 ----------------
    v2f acc[4][TN];
#pragma unroll
    for (int f = 0; f < 4; ++f)
#pragma unroll
        for (int q = 0; q < TN; ++q) acc[f][q] = (v2f){0.0f, 0.0f};

    for (int n0 = 0; n0 < HID; n0 += 4) {
        const float* prow = &ldsP[n0 * 32 + (o1 ^ (((n0 >> 2) & 3) << 3))];
        const float* wrow = LW2 + n0 * HID + k0;
#pragma unroll
        for (int j = 0; j < 4; ++j) {
            v4f pA = *(const v4f*)(prow + j * 32);
            v4f pB = *(const v4f*)(prow + j * 32 + 4);
            v4f w4 = *(const v4f*)(wrow + j * HID);
            v2f wlo = __builtin_shufflevector(w4, w4, 0, 1);
            v2f whi = __builtin_shufflevector(w4, w4, 2, 3);
            v2f hv = __builtin_shufflevector(pA, pA, 0, 1);
            v2f i1 = __builtin_shufflevector(pA, pA, 2, 3);
            v2f i2 = __builtin_shufflevector(pB, pB, 0, 1);
            v2f i3 = __builtin_shufflevector(pB, pB, 2, 3);
            ACC4(acc[0], hv);
            ACC4(acc[1], i1);
            ACC4(acc[2], i2);
            ACC4(acc[3], i3);
        }
    }
    __syncthreads();   // all pass-1 LDS reads complete

    // ---------------- pass-1 epilogue: H += P^T diag(m2) P; stash {g2, m2*(P.td)} ----------------
    v2f Hp[6];
#pragma unroll
    for (int i = 0; i < 6; ++i) Hp[i] = (v2f){0.0f, 0.0f};
    const v2f td0v = *(const v2f*)&xs2[0][s0];
    const v2f td1v = *(const v2f*)&xs2[1][s0];
    const v2f td2v = *(const v2f*)&xs2[2][s0];
    {
        v4f b2v = *(const v4f*)(Lb2 + k0);
        v4f w3v = *(const v4f*)(LW3 + k0);
#pragma unroll
        for (int q = 0; q < TN; ++q) {
            v2f a2 = acc[0][q] + b2v[q];
            v2f h2; h2.x = fast_tanh(a2.x); h2.y = fast_tanh(a2.y);
            v2f t2 = 1.0f - h2 * h2;
            v2f g2 = t2 * w3v[q];
            v2f m2 = -2.0f * h2 * g2;
            v2f P0 = acc[1][q], P1 = acc[2][q], P2 = acc[3][q];
            v2f m2P0 = m2 * P0, m2P1 = m2 * P1;
            Hp[0] += m2P0 * P0;         // (0,0)
            Hp[1] += m2P0 * P1;         // (0,1)
            Hp[2] += m2P1 * P1;         // (1,1)
            Hp[3] += m2P0 * P2;         // (0,2)
            Hp[4] += m2P1 * P2;         // (1,2)
            Hp[5] += m2 * P2 * P2;      // (2,2)
            v2f ptd = td0v * P0 + td1v * P1 + td2v * P2;
            v2f pd  = m2 * ptd;
            *(v4f*)&ldsP[(k0 + q) * 32 + (o2 ^ sw2)] = (v4f){ g2.x, g2.y, pd.x, pd.y };
        }
    }
    __syncthreads();

    // ---------------- pass 2: u = W2 g2,  w = W2 (m2 * P.td) ----------------
#pragma unroll
    for (int f = 0; f < 2; ++f)
#pragma unroll
        for (int q = 0; q < TN; ++q) acc[f][q] = (v2f){0.0f, 0.0f};

    for (int n0 = 0; n0 < HID; n0 += 4) {
        const float* prow = &ldsP[n0 * 32 + (o2 ^ (((n0 >> 2) & 3) << 2))];
        const float* wrow = W2T + n0 * HID + k0;
#pragma unroll
        for (int j = 0; j < 4; ++j) {
            v4f p  = *(const v4f*)(prow + j * 32);
            v4f w4 = *(const v4f*)(wrow + j * HID);
            v2f wlo = __builtin_shufflevector(w4, w4, 0, 1);
            v2f whi = __builtin_shufflevector(w4, w4, 2, 3);
            v2f g2v = __builtin_shufflevector(p, p, 0, 1);
            v2f pdv = __builtin_shufflevector(p, p, 2, 3);
            ACC4(acc[0], g2v);
            ACC4(acc[1], pdv);
        }
    }

    // ---------------- pass-2 epilogue: diag terms, dL, C.td ----------------
    v2f dLp[3], ctp[3];
#pragma unroll
    for (int i = 0; i < 3; ++i) { dLp[i] = (v2f){0,0}; ctp[i] = (v2f){0,0}; }
    {
        v4f wd0 = *(const v4f*)(LW1 + 0 * HID + k0);
        v4f wd1 = *(const v4f*)(LW1 + 1 * HID + k0);
        v4f wd2 = *(const v4f*)(LW1 + 2 * HID + k0);
        v4f wt0 = *(const v4f*)(LW1 + 6 * HID + k0);
        v4f wt1 = *(const v4f*)(LW1 + 7 * HID + k0);
        v4f wt2 = *(const v4f*)(LW1 + 8 * HID + k0);
#pragma unroll
        for (int q = 0; q < TN; ++q) {
            v2f h1; h1.x = h1r[0][q]; h1.y = h1r[1][q];
            v2f t1 = 1.0f - h1 * h1;
            v2f u  = acc[0][q];
            v2f w  = acc[1][q];
            v2f g1 = u * t1;
            dLp[0] += g1 * wt0[q]; dLp[1] += g1 * wt1[q]; dLp[2] += g1 * wt2[q];
            v2f cf = -2.0f * u * h1 * t1;            // diag-term coefficient
            v2f wdtd = td0v * wd0[q] + td1v * wd1[q] + td2v * wd2[q];
            v2f ct = t1 * w + cf * wdtd;             // (C theta_dot) integrand
            ctp[0] += ct * wt0[q]; ctp[1] += ct * wt1[q]; ctp[2] += ct * wt2[q];
            float w00 = wd0[q] * wd0[q], w01 = wd0[q] * wd1[q], w11 = wd1[q] * wd1[q];
            float w02 = wd0[q] * wd2[q], w12 = wd1[q] * wd2[q], w22 = wd2[q] * wd2[q];
            Hp[0] += cf * w00; Hp[1] += cf * w01; Hp[2] += cf * w11;
            Hp[3] += cf * w02; Hp[4] += cf * w12; Hp[5] += cf * w22;
        }
    }

    // ---------------- reduce over 64 column-threads ----------------
#pragma unroll
    for (int i = 0; i < 6; ++i) {
        v2f v = red64(Hp[i]);
        if (c == 0) { red[s0][i] = v.x; red[s0 + 1][i] = v.y; }
    }
#pragma unroll
    for (int i = 0; i < 3; ++i) {
        v2f v = red64(dLp[i]);
        if (c == 0) { red[s0][6 + i] = v.x; red[s0 + 1][6 + i] = v.y; }
    }
#pragma unroll
    for (int i = 0; i < 3; ++i) {
        v2f v = red64(ctp[i]);
        if (c == 0) { red[s0][9 + i] = v.x; red[s0 + 1][9 + i] = v.y; }
    }
    __syncthreads();

    // ---------------- per-sample 3x3 symmetric solve (fp64) ----------------
    if (tid < SB) {
        int s = tid;
        int gs = sg0 + s;
        double Ha = red[s][0], Hb = red[s][1], Hd = red[s][2];
        double Hc = red[s][3], He = red[s][4], Hf = red[s][5];
        double rhs[3];
#pragma unroll
        for (int i = 0; i < 3; ++i) {
            rhs[i] = (double)g_tau[gs * 3 + i] + (double)red[s][12 + i] + (double)Bb2[i]
                   + (double)red[s][6 + i]
                   - (double)red[s][9 + i];
        }
        double I00 = Hd * Hf - He * He;
        double I01 = Hc * He - Hb * Hf;
        double I02 = Hb * He - Hc * Hd;
        double I11 = Ha * Hf - Hc * Hc;
        double I12 = Hb * Hc - Ha * He;
        double I22 = Ha * Hd - Hb * Hb;
        double det = Ha * I00 + Hb * I01 + Hc * I02;
        double inv = 1.0 / det;
        out[gs * 3 + 0] = (float)((I00 * rhs[0] + I01 * rhs[1] + I02 * rhs[2]) * inv);
        out[gs * 3 + 1] = (float)((I01 * rhs[0] + I11 * rhs[1] + I12 * rhs[2]) * inv);
        out[gs * 3 + 2] = (float)((I02 * rhs[0] + I12 * rhs[1] + I22 * rhs[2]) * inv);
    }
}

extern "C" void kernel_launch(void* const* d_in, const int* in_sizes, int n_in,
                              void* d_out, int out_size, void* d_ws, size_t ws_size,
                              hipStream_t stream) {
    const float* td  = (const float*)d_in[0];
    const float* sd  = (const float*)d_in[1];
    const float* th  = (const float*)d_in[2];
    const float* z   = (const float*)d_in[3];
    const float* s_  = (const float*)d_in[4];
    const float* sdd = (const float*)d_in[5];
    const float* tau = (const float*)d_in[6];
    const float* LW1 = (const float*)d_in[7];
    const float* Lb1 = (const float*)d_in[8];
    const float* LW2 = (const float*)d_in[9];
    const float* Lb2 = (const float*)d_in[10];
    const float* LW3 = (const float*)d_in[11];
    // d_in[12] = Lb3 (unused: constant bias does not affect any derivative)
    const float* BW1 = (const float*)d_in[13];
    const float* Bb1 = (const float*)d_in[14];
    const float* BW2 = (const float*)d_in[15];
    const float* Bb2 = (const float*)d_in[16];
    float* outp = (float*)d_out;
    float* W2T  = (float*)d_ws;   // 256*256*4 = 256 KB scratch

    transpose256<<<dim3(64), dim3(256), 0, stream>>>(LW2, W2T);

    const int Btot = in_sizes[0] / 3;
    const int nblk = Btot / SB;
    lnn_fused<<<dim3(nblk), dim3(256), 0, stream>>>(
        td, sd, th, z, s_, sdd, tau, LW1, Lb1, LW2, Lb2, LW3,
        BW1, Bb1, BW2, Bb2, W2T, outp);
}